// Round 15
// baseline (90.469 us; speedup 1.0000x reference)
//
#include <hip/hip_runtime.h>
#include <stdint.h>

typedef __attribute__((ext_vector_type(4))) float f32x4;
typedef __attribute__((ext_vector_type(4))) unsigned int u32x4;
typedef __attribute__((ext_vector_type(2))) long long i64x2;
typedef long long i64_t;

#define NB 16
#define NC 128
#define NH 128
#define NW 128
#define WPL 66   // local padded width (64 cols + 2 halo)

__device__ __forceinline__ int swz7(int wp) { return (wp ^ (wp >> 3)) & 7; }

// ---------------- prep: wfrag (B sign bytes) + sf = mean|w| + theta ----------------
// wfrag flat byte f = p*8192 + kb*2048 + nip*1024 + l*16 + nl*8 + j   (ni = nip*2+nl)
// o = ni*16 + (l&15)
// plain-unit K mapping (validated r7): instr kb, lane lg holds 8-block
// {2lg,2lg+1,2lg+8,2lg+9}[kb]  ->  c = lg*16 + (kb&1)*8 + (kb>>1)*64 + j
__global__ __launch_bounds__(256) void k_prep(const float* __restrict__ cw,
                                              const float* __restrict__ b1,
                                              const float* __restrict__ pa,
                                              const float* __restrict__ b2,
                                              float* __restrict__ sf,
                                              float* __restrict__ theta,
                                              unsigned char* __restrict__ wf) {
    int b = blockIdx.x, t = threadIdx.x;    // 288 blocks
    int f = b * 256 + t;                    // < 73728
    int j   = f & 7;
    int kb  = (f >> 11) & 3;
    int p   = f >> 13;
    int l   = (f >> 4) & 63;
    int lg = (l >> 4) & 3;
    int nl  = (f >> 3) & 1;
    int nip = (f >> 10) & 1;
    int o = (nip * 2 + nl) * 16 + (l & 15);
    int c = lg * 16 + (kb & 1) * 8 + (kb >> 1) * 64 + j;   // plain-unit K mapping
    float wv = cw[o * 1152 + c * 9 + p];
    wf[f] = wv > 0.f ? (unsigned char)0x38
                     : (wv < 0.f ? (unsigned char)0xB8 : (unsigned char)0x00);
    if (b < 64) {                           // sf[b] = mean|w| over 1152
        __shared__ float red[4];
        const float* pp = cw + b * 1152;
        float s = 0.f;
        for (int i = t; i < 1152; i += 256) s += fabsf(pp[i]);
#pragma unroll
        for (int off = 32; off > 0; off >>= 1) s += __shfl_down(s, off);
        if ((t & 63) == 0) red[t >> 6] = s;
        __syncthreads();
        if (t == 0) sf[b] = (red[0] + red[1] + red[2] + red[3]) * (1.0f / 1152.0f);
    }
    if (b == 64 && t < NC) {                // theta: sign(prelu(v+b1)+b2) == sign(v - theta)
        float B1 = b1[t], A = pa[t], B2 = b2[t];   // prelu slope a>0 -> monotone
        theta[t] = (-B2 >= 0.f) ? (-B1 - B2) : (-B1 - B2 / A);
    }
}

__device__ __forceinline__ unsigned int pk8(float v, float th) {
    return v > th ? 0x38u : (v < th ? 0xB8u : 0u);
}

// ---------------- fused, 64-col tile, 4 blocks/CU: stage signs of 4 padded rows x 66
// cols into LDS (swz7 at actual LOCAL column, both sides), shortcut in 32 regs,
// M=32 MFMA per wave, epilogue via Tt[64][36] tiles, single out write. ----------------
__global__ __launch_bounds__(256, 4) void k_fused(
    const float* __restrict__ x, const float* __restrict__ theta,
    const float* __restrict__ pw, const unsigned char* __restrict__ wf,
    const float* __restrict__ sf, float* __restrict__ out) {
    __shared__ __align__(16) unsigned char AT[36864];   // staging 33792 | Tt 4x9216
    int bxr = blockIdx.x;                   // 2048
    int bx = (bxr & 7) * 256 + (bxr >> 3);  // XCD swizzle (2048 % 8 == 0, bijective)
    int nb = bx >> 7;
    int rem = bx & 127;
    int h2b = rem >> 1;                     // output row pair
    int ch = rem & 1;                       // column half (cols 64ch .. 64ch+63)
    int t = threadIdx.x;
    int wid = t >> 6;
    int l = t & 63;
    int lr = l & 15, lg = l >> 4;

    // ---- halo columns wp_local 0 and 65 (zero pad at image edge, else real data) ----
    if (t < 64) {
        int u = t >> 3;                     // channel unit 16u..16u+15
        int rho = (t >> 1) & 3;
        int side = t & 1;
        int wp = side ? (WPL - 1) : 0;
        int gpc = 64 * ch + wp;             // global padded col (0..129)
        int hh = 2 * h2b + rho - 1;
        u32x4 v = {0u, 0u, 0u, 0u};
        if (gpc > 0 && gpc < 129 && hh >= 0 && hh < NH) {
            const float* xq = x + ((size_t)nb * NC + u * 16) * (NH * NW)
                                + (size_t)hh * NW + (gpc - 1);
            float va[16];
#pragma unroll
            for (int c = 0; c < 16; ++c) va[c] = xq[(size_t)c * (NH * NW)];
            f32x4 ta = *(const f32x4*)(theta + u * 16);
            f32x4 tb = *(const f32x4*)(theta + u * 16 + 4);
            f32x4 tc = *(const f32x4*)(theta + u * 16 + 8);
            f32x4 td = *(const f32x4*)(theta + u * 16 + 12);
            v.x = pk8(va[0], ta.x) | (pk8(va[1], ta.y) << 8) |
                  (pk8(va[2], ta.z) << 16) | (pk8(va[3], ta.w) << 24);
            v.y = pk8(va[4], tb.x) | (pk8(va[5], tb.y) << 8) |
                  (pk8(va[6], tb.z) << 16) | (pk8(va[7], tb.w) << 24);
            v.z = pk8(va[8], tc.x) | (pk8(va[9], tc.y) << 8) |
                  (pk8(va[10], tc.z) << 16) | (pk8(va[11], tc.w) << 24);
            v.w = pk8(va[12], td.x) | (pk8(va[13], td.y) << 8) |
                  (pk8(va[14], td.z) << 16) | (pk8(va[15], td.w) << 24);
        }
        *(u32x4*)(AT + (size_t)(rho * WPL + wp) * NC + ((u ^ swz7(wp)) << 4)) = v;
    }

    // ---- main staging: thread (w4 = t&15, cg = t>>4) covers cols 4w4..4w4+3, ch 8cg..+7 ----
    int w4 = t & 15, cg = t >> 4;
    int uu = cg >> 1, half = cg & 1;        // 16B unit and 8B half within it
    const float* xbase = x + ((size_t)nb * NC + cg * 8) * (NH * NW) + 64 * ch + 4 * w4;
    f32x4 th0 = *(const f32x4*)(theta + cg * 8);
    f32x4 th1 = *(const f32x4*)(theta + cg * 8 + 4);
    f32x4 pw0 = *(const f32x4*)(pw + cg * 8);
    f32x4 pw1 = *(const f32x4*)(pw + cg * 8 + 4);
    float pwf[8] = {pw0.x, pw0.y, pw0.z, pw0.w, pw1.x, pw1.y, pw1.z, pw1.w};
    float sc0[4][4], sc1[4][4];             // shortcut regs, statically indexed

#define LOADX8(HH) \
    { const float* xp = xbase + (size_t)(HH) * NW; \
      _Pragma("unroll") for (int cc = 0; cc < 8; ++cc) \
          X[cc] = *(const f32x4*)(xp + (size_t)cc * (NH * NW)); }
#define PACKROW(RHO) \
    _Pragma("unroll") for (int ww = 0; ww < 4; ++ww) { \
        int wp = 4 * w4 + 1 + ww; \
        uint2 v; \
        v.x = pk8(X[0][ww], th0.x) | (pk8(X[1][ww], th0.y) << 8) | \
              (pk8(X[2][ww], th0.z) << 16) | (pk8(X[3][ww], th0.w) << 24); \
        v.y = pk8(X[4][ww], th1.x) | (pk8(X[5][ww], th1.y) << 8) | \
              (pk8(X[6][ww], th1.z) << 16) | (pk8(X[7][ww], th1.w) << 24); \
        *(uint2*)(AT + (size_t)((RHO) * WPL + wp) * NC + ((uu ^ swz7(wp)) << 4) + half * 8) = v; \
    }
#define ZEROROW(RHO) \
    { uint2 z = {0u, 0u}; \
      _Pragma("unroll") for (int ww = 0; ww < 4; ++ww) { \
          int wp = 4 * w4 + 1 + ww; \
          *(uint2*)(AT + (size_t)((RHO) * WPL + wp) * NC + ((uu ^ swz7(wp)) << 4) + half * 8) = z; } }
#define SCROW(SC) \
    _Pragma("unroll") for (int i = 0; i < 4; ++i) { \
        float wa = pwf[2 * i], wb = pwf[2 * i + 1]; \
        _Pragma("unroll") for (int ww = 0; ww < 4; ++ww) \
            SC[i][ww] = wa * X[2 * i][ww] + wb * X[2 * i + 1][ww]; \
    }

    if (h2b > 0) {                          // row 0 (top halo)
        f32x4 X[8];
        LOADX8(2 * h2b - 1)
        PACKROW(0)
    } else ZEROROW(0)
    {                                       // row 1 = output row 0 (+shortcut regs)
        f32x4 X[8];
        LOADX8(2 * h2b)
        PACKROW(1)
        SCROW(sc0)
    }
    {                                       // row 2 = output row 1 (+shortcut regs)
        f32x4 X[8];
        LOADX8(2 * h2b + 1)
        PACKROW(2)
        SCROW(sc1)
    }
    if (h2b < 63) {                         // row 3 (bottom halo)
        f32x4 X[8];
        LOADX8(2 * h2b + 2)
        PACKROW(3)
    } else ZEROROW(3)

    float sfr[4];
#pragma unroll
    for (int ni = 0; ni < 4; ++ni) sfr[ni] = sf[ni * 16 + lr];

    int w0l = 32 * (wid & 1);               // wave: row = wid>>1, col-half32 = wid&1
    f32x4 acc[2][4];
    f32x4 zero = {0.f, 0.f, 0.f, 0.f};
#pragma unroll
    for (int mi = 0; mi < 2; ++mi)
#pragma unroll
        for (int ni = 0; ni < 4; ++ni) acc[mi][ni] = zero;
    __syncthreads();

    // ---- MFMA phase: M=32 per wave, per-mi swizzle at actual LOCAL column ----
#pragma unroll
    for (int p = 0; p < 9; ++p) {
        int kh = p / 3, kw = p % 3;         // constants after unroll
        int rho = (wid >> 1) + kh;          // local padded row 0..3
        int wpb = w0l + kw + lr;            // local padded col of this lane's pixel
        const unsigned char* ap = AT + (size_t)(rho * WPL + wpb) * NC;
        const unsigned char* brow = wf + p * 8192 + l * 16;
        i64_t bfr[4][4];
#pragma unroll
        for (int kb = 0; kb < 4; ++kb) {    // B: 16B/lane coalesced, L2-hot
            i64x2 b01 = *(const i64x2*)(brow + kb * 2048);
            i64x2 b23 = *(const i64x2*)(brow + kb * 2048 + 1024);
            bfr[kb][0] = b01.x; bfr[kb][1] = b01.y;
            bfr[kb][2] = b23.x; bfr[kb][3] = b23.y;
        }
#pragma unroll
        for (int mi = 0; mi < 2; ++mi) {    // 2 x ds_read_b128 = all 4 kb fragments
            int s7m = swz7(wpb + mi * 16);  // swizzle of the column actually read
            i64x2 a01 = *(const i64x2*)(ap + mi * 2048 + ((lg ^ s7m) << 4));
            i64x2 a23 = *(const i64x2*)(ap + mi * 2048 + (((lg + 4) ^ s7m) << 4));
            i64_t af[4] = {a01.x, a01.y, a23.x, a23.y};
#pragma unroll
            for (int kb = 0; kb < 4; ++kb)
#pragma unroll
                for (int ni = 0; ni < 4; ++ni)
                    acc[mi][ni] = __builtin_amdgcn_mfma_f32_16x16x32_fp8_fp8(
                        af[kb], bfr[kb][ni], acc[mi][ni], 0, 0, 0);
        }
    }
    __syncthreads();                        // A-tile dead; AT becomes 4 x Tt[64][36]

    // ---- epilogue: per-wave conv tile (f32x4, stride 36 floats = 16B-aligned rows) ----
    float (*Tt)[36] = (float (*)[36])(AT + wid * 9216);
#pragma unroll
    for (int mi = 0; mi < 2; ++mi)
#pragma unroll
        for (int ni = 0; ni < 4; ++ni)
            *(f32x4*)&Tt[ni * 16 + lr][mi * 16 + lg * 4] = acc[mi][ni] * sfr[ni];
    __syncthreads();

    // staging-mapped readout: thread (w4, cg) owns o in [4cg,4cg+4), cols 4w4..4w4+3
    int colh_t = w4 >> 3, w4l = w4 & 7;
#define EPIROW(R2, SC) { \
    const float (*Ts)[36] = (const float (*)[36])(AT + ((R2) * 2 + colh_t) * 9216); \
    float* obr = out + (((size_t)nb * 256 + (R2) * 2) * 64 + h2b) * 64 + 32 * ch + 2 * w4; \
    _Pragma("unroll") for (int i = 0; i < 4; ++i) { \
        int o = 4 * cg + i; \
        f32x4 cv = *(const f32x4*)&Ts[o][4 * w4l]; \
        float2 A = {cv.x + SC[i][0], cv.z + SC[i][2]}; \
        float2 B = {cv.y + SC[i][1], cv.w + SC[i][3]}; \
        *(float2*)(obr + (size_t)o * 16384)        = A; \
        *(float2*)(obr + (size_t)o * 16384 + 4096) = B; \
    } }
    EPIROW(0, sc0)
    EPIROW(1, sc1)
}

extern "C" void kernel_launch(void* const* d_in, const int* in_sizes, int n_in,
                              void* d_out, int out_size, void* d_ws, size_t ws_size,
                              hipStream_t stream) {
    const float* x  = (const float*)d_in[0];
    const float* b1 = (const float*)d_in[1];
    const float* pa = (const float*)d_in[2];
    const float* b2 = (const float*)d_in[3];
    const float* cw = (const float*)d_in[4];
    const float* pw = (const float*)d_in[5];
    float* out = (float*)d_out;
    // ws layout: [0,256) sf | [256,768) theta | [768, 768+73728) wfrag
    float* sf = (float*)d_ws;
    float* theta = (float*)((char*)d_ws + 256);
    unsigned char* wfr = (unsigned char*)d_ws + 768;

    k_prep<<<288, 256, 0, stream>>>(cw, b1, pa, b2, sf, theta, wfr);
    k_fused<<<2048, 256, 0, stream>>>(x, theta, pw, wfr, sf, out);
}

// Round 16
// 81.521 us; speedup vs baseline: 1.1098x; 1.1098x over previous
//
#include <hip/hip_runtime.h>
#include <stdint.h>

typedef __attribute__((ext_vector_type(4))) float f32x4;
typedef __attribute__((ext_vector_type(4))) unsigned int u32x4;
typedef __attribute__((ext_vector_type(4))) int i32x4;

#define NB 16
#define NC 128
#define NH 128
#define NW 128
#define WP 130

__device__ __forceinline__ int swz7(int wp) { return (wp ^ (wp >> 3)) & 7; }

// ---------------- prep: wfrag (B sign bytes, i8) + sf = mean|w| + theta ----------------
// i8 K=64 layout: wfrag byte f = p*8192 + m*4096 + ni*1024 + l*16 + b
// o = ni*16 + (l&15), c = m*64 + (l>>4)*16 + b   (consistent with A unit layout;
// dot-product is invariant to the HW's actual k-permutation as long as A/B match)
__global__ __launch_bounds__(256) void k_prep(const float* __restrict__ cw,
                                              const float* __restrict__ b1,
                                              const float* __restrict__ pa,
                                              const float* __restrict__ b2,
                                              float* __restrict__ sf,
                                              float* __restrict__ theta,
                                              unsigned char* __restrict__ wf) {
    int b = blockIdx.x, t = threadIdx.x;    // 288 blocks
    int f = b * 256 + t;                    // < 73728
    int bb  = f & 15;
    int l   = (f >> 4) & 63;
    int ni  = (f >> 10) & 3;
    int m   = (f >> 12) & 1;
    int p   = f >> 13;
    int o = ni * 16 + (l & 15);
    int c = m * 64 + (l >> 4) * 16 + bb;
    float wv = cw[o * 1152 + c * 9 + p];
    wf[f] = wv > 0.f ? (unsigned char)0x01
                     : (wv < 0.f ? (unsigned char)0xFF : (unsigned char)0x00);
    if (b < 64) {                           // sf[b] = mean|w| over 1152
        __shared__ float red[4];
        const float* pp = cw + b * 1152;
        float s = 0.f;
        for (int i = t; i < 1152; i += 256) s += fabsf(pp[i]);
#pragma unroll
        for (int off = 32; off > 0; off >>= 1) s += __shfl_down(s, off);
        if ((t & 63) == 0) red[t >> 6] = s;
        __syncthreads();
        if (t == 0) sf[b] = (red[0] + red[1] + red[2] + red[3]) * (1.0f / 1152.0f);
    }
    if (b == 64 && t < NC) {                // theta: sign(prelu(v+b1)+b2) == sign(v - theta)
        float B1 = b1[t], A = pa[t], B2 = b2[t];   // prelu slope a>0 -> monotone
        theta[t] = (-B2 >= 0.f) ? (-B1 - B2) : (-B1 - B2 / A);
    }
}

__device__ __forceinline__ unsigned int pki8(float v, float th) {
    return v > th ? 0x01u : (v < th ? 0xFFu : 0u);
}

// ---------------- fused (r14 structure, i8 MFMA): stage signs of 4 padded x-rows into
// LDS (coalesced f32x4, register transpose, two-sided swz7), shortcut in 64 regs,
// mfma_i32_16x16x64_i8 (half the instructions of fp8 K=32), epilogue: Tt tiles ->
// staging-mapped readout -> single coalesced out write. No global reads in epilogue. ----
__global__ __launch_bounds__(256, 2) void k_fused(
    const float* __restrict__ x, const float* __restrict__ theta,
    const float* __restrict__ pw, const unsigned char* __restrict__ wf,
    const float* __restrict__ sf, float* __restrict__ out) {
    __shared__ __align__(16) unsigned char AT[69632];   // staging 66560 | Tt 4x17408
    int bxr = blockIdx.x;
    int bx = (bxr & 7) * 128 + (bxr >> 3);  // XCD swizzle (1024 % 8 == 0, bijective)
    int nb = bx >> 6;
    int h2b = bx & 63;
    int t = threadIdx.x;
    int wid = t >> 6;
    int l = t & 63;
    int lr = l & 15, lg = l >> 4;

    // ---- pad columns wp=0, 129 (zeros, swizzled slots) ----
    if (t < 64) {
        int rho = t >> 4, side = (t >> 3) & 1, u = t & 7;
        int wp = side ? (WP - 1) : 0;
        u32x4 z = {0u, 0u, 0u, 0u};
        *(u32x4*)(AT + (size_t)(rho * WP + wp) * NC + ((u ^ swz7(wp)) << 4)) = z;
    }

    // ---- staging: thread (w4 = t&31, cg = t>>5) ----
    int w4 = t & 31, cg = t >> 5;
    const float* xbase = x + ((size_t)nb * NC + cg * 16) * (NH * NW) + 4 * w4;
    f32x4 th0 = *(const f32x4*)(theta + cg * 16);
    f32x4 th1 = *(const f32x4*)(theta + cg * 16 + 4);
    f32x4 th2 = *(const f32x4*)(theta + cg * 16 + 8);
    f32x4 th3 = *(const f32x4*)(theta + cg * 16 + 12);
    f32x4 p0 = *(const f32x4*)(pw + cg * 16);
    f32x4 p1 = *(const f32x4*)(pw + cg * 16 + 4);
    f32x4 p2 = *(const f32x4*)(pw + cg * 16 + 8);
    f32x4 p3 = *(const f32x4*)(pw + cg * 16 + 12);
    float pwv[16] = {p0.x, p0.y, p0.z, p0.w, p1.x, p1.y, p1.z, p1.w,
                     p2.x, p2.y, p2.z, p2.w, p3.x, p3.y, p3.z, p3.w};
    float sc0[8][4], sc1[8][4];             // shortcut regs, statically indexed

#define LOADX(HH) \
    { const float* xp = xbase + (size_t)(HH) * NW; \
      _Pragma("unroll") for (int cc = 0; cc < 16; ++cc) \
          X[cc] = *(const f32x4*)(xp + (size_t)cc * (NH * NW)); }
#define PACKROW(RHO) \
    _Pragma("unroll") for (int ww = 0; ww < 4; ++ww) { \
        int wp = 4 * w4 + ww + 1; \
        u32x4 v; \
        v.x = pki8(X[0][ww], th0.x) | (pki8(X[1][ww], th0.y) << 8) | \
              (pki8(X[2][ww], th0.z) << 16) | (pki8(X[3][ww], th0.w) << 24); \
        v.y = pki8(X[4][ww], th1.x) | (pki8(X[5][ww], th1.y) << 8) | \
              (pki8(X[6][ww], th1.z) << 16) | (pki8(X[7][ww], th1.w) << 24); \
        v.z = pki8(X[8][ww], th2.x) | (pki8(X[9][ww], th2.y) << 8) | \
              (pki8(X[10][ww], th2.z) << 16) | (pki8(X[11][ww], th2.w) << 24); \
        v.w = pki8(X[12][ww], th3.x) | (pki8(X[13][ww], th3.y) << 8) | \
              (pki8(X[14][ww], th3.z) << 16) | (pki8(X[15][ww], th3.w) << 24); \
        *(u32x4*)(AT + (size_t)((RHO) * WP + wp) * NC + ((cg ^ swz7(wp)) << 4)) = v; \
    }
#define ZEROROW(RHO) \
    { u32x4 z = {0u, 0u, 0u, 0u}; \
      _Pragma("unroll") for (int ww = 0; ww < 4; ++ww) { \
          int wp = 4 * w4 + ww + 1; \
          *(u32x4*)(AT + (size_t)((RHO) * WP + wp) * NC + ((cg ^ swz7(wp)) << 4)) = z; } }
#define SCROW(SC) \
    _Pragma("unroll") for (int i = 0; i < 8; ++i) { \
        float wa = pwv[2 * i], wb = pwv[2 * i + 1]; \
        _Pragma("unroll") for (int ww = 0; ww < 4; ++ww) \
            SC[i][ww] = wa * X[2 * i][ww] + wb * X[2 * i + 1][ww]; \
    }

    if (h2b > 0) {                          // row 0 (top halo)
        f32x4 X[16];
        LOADX(2 * h2b - 1)
        PACKROW(0)
    } else ZEROROW(0)
    {                                       // row 1 = output row 0 (+shortcut regs)
        f32x4 X[16];
        LOADX(2 * h2b)
        PACKROW(1)
        SCROW(sc0)
    }
    {                                       // row 2 = output row 1 (+shortcut regs)
        f32x4 X[16];
        LOADX(2 * h2b + 1)
        PACKROW(2)
        SCROW(sc1)
    }
    if (h2b < 63) {                         // row 3 (bottom halo)
        f32x4 X[16];
        LOADX(2 * h2b + 2)
        PACKROW(3)
    } else ZEROROW(3)

    float sfr[4];
#pragma unroll
    for (int ni = 0; ni < 4; ++ni) sfr[ni] = sf[ni * 16 + lr];

    int w0 = (wid & 1) * 64;                // output col base for this wave
    i32x4 acc[4][4];
    i32x4 zero = {0, 0, 0, 0};
#pragma unroll
    for (int mi = 0; mi < 4; ++mi)
#pragma unroll
        for (int ni = 0; ni < 4; ++ni) acc[mi][ni] = zero;
    __syncthreads();

    // ---- MFMA phase: i8 K=64, 2 instrs per (p,mi,ni); per-mi swizzle at actual col ----
#pragma unroll
    for (int p = 0; p < 9; ++p) {
        int kh = p / 3, kw = p % 3;         // constants after unroll
        int rho = (wid >> 1) + kh;          // local padded row 0..3
        int wp = w0 + kw + lr;
        const unsigned char* ap = AT + (size_t)(rho * WP + wp) * NC;
        const unsigned char* brow = wf + p * 8192 + l * 16;
        i32x4 bfr[2][4];
#pragma unroll
        for (int m = 0; m < 2; ++m)         // B: 16B/lane coalesced, L2-hot
#pragma unroll
            for (int ni = 0; ni < 4; ++ni)
                bfr[m][ni] = *(const i32x4*)(brow + m * 4096 + ni * 1024);
#pragma unroll
        for (int mi = 0; mi < 4; ++mi) {    // 2 x ds_read_b128 = both K-halves
            int s7m = swz7(wp + mi * 16);   // swizzle of the column actually read
            i32x4 a0 = *(const i32x4*)(ap + mi * 2048 + ((lg ^ s7m) << 4));       // ch 16lg..+15
            i32x4 a1 = *(const i32x4*)(ap + mi * 2048 + (((lg + 4) ^ s7m) << 4)); // ch 64+16lg..
#pragma unroll
            for (int ni = 0; ni < 4; ++ni) {
                acc[mi][ni] = __builtin_amdgcn_mfma_i32_16x16x64_i8(
                    a0, bfr[0][ni], acc[mi][ni], 0, 0, 0);
                acc[mi][ni] = __builtin_amdgcn_mfma_i32_16x16x64_i8(
                    a1, bfr[1][ni], acc[mi][ni], 0, 0, 0);
            }
        }
    }
    __syncthreads();                        // A-tile dead; AT becomes 4 x Tt[64][68]

    // ---- epilogue: full per-wave conv tile (i32 -> f32 * sf, f32x4 LDS writes) ----
    float (*Tt)[68] = (float (*)[68])(AT + wid * 17408);
#pragma unroll
    for (int mi = 0; mi < 4; ++mi)
#pragma unroll
        for (int ni = 0; ni < 4; ++ni) {
            f32x4 cv;
            cv.x = (float)acc[mi][ni].x * sfr[ni];
            cv.y = (float)acc[mi][ni].y * sfr[ni];
            cv.z = (float)acc[mi][ni].z * sfr[ni];
            cv.w = (float)acc[mi][ni].w * sfr[ni];
            *(f32x4*)&Tt[ni * 16 + lr][mi * 16 + lg * 4] = cv;
        }
    __syncthreads();

    // staging-mapped readout: thread (w4, cg) owns o in [8cg,8cg+8), cols 4w4..+3
    int wha = w4 >> 4, w4l = w4 & 15;
#define EPIROW(R2, SC) { \
    const float (*Ts)[68] = (const float (*)[68])(AT + ((R2) * 2 + wha) * 17408); \
    float* obr = out + (((size_t)nb * 256 + (R2) * 2) * 64 + h2b) * 64 + 2 * w4; \
    _Pragma("unroll") for (int i = 0; i < 8; ++i) { \
        int o = 8 * cg + i; \
        f32x4 cv = *(const f32x4*)&Ts[o][4 * w4l]; \
        float2 A = {cv.x + SC[i][0], cv.z + SC[i][2]}; \
        float2 B = {cv.y + SC[i][1], cv.w + SC[i][3]}; \
        *(float2*)(obr + (size_t)o * 16384)        = A; \
        *(float2*)(obr + (size_t)o * 16384 + 4096) = B; \
    } }
    EPIROW(0, sc0)
    EPIROW(1, sc1)
}

extern "C" void kernel_launch(void* const* d_in, const int* in_sizes, int n_in,
                              void* d_out, int out_size, void* d_ws, size_t ws_size,
                              hipStream_t stream) {
    const float* x  = (const float*)d_in[0];
    const float* b1 = (const float*)d_in[1];
    const float* pa = (const float*)d_in[2];
    const float* b2 = (const float*)d_in[3];
    const float* cw = (const float*)d_in[4];
    const float* pw = (const float*)d_in[5];
    float* out = (float*)d_out;
    // ws layout: [0,256) sf | [256,768) theta | [768, 768+73728) wfrag
    float* sf = (float*)d_ws;
    float* theta = (float*)((char*)d_ws + 256);
    unsigned char* wfr = (unsigned char*)d_ws + 768;

    k_prep<<<288, 256, 0, stream>>>(cw, b1, pa, b2, sf, theta, wfr);
    k_fused<<<1024, 256, 0, stream>>>(x, theta, pw, wfr, sf, out);
}

// Round 17
// 79.453 us; speedup vs baseline: 1.1387x; 1.0260x over previous
//
#include <hip/hip_runtime.h>
#include <stdint.h>

typedef __attribute__((ext_vector_type(4))) float f32x4;
typedef __attribute__((ext_vector_type(4))) unsigned int u32x4;
typedef __attribute__((ext_vector_type(4))) int i32x4;

#define NB 16
#define NC 128
#define NH 128
#define NW 128
#define WP 130

__device__ __forceinline__ int swz7(int wp) { return (wp ^ (wp >> 3)) & 7; }

// ---------------- prep: wfrag (B sign bytes, i8) + sf = mean|w| + theta ----------------
// i8 K=64 layout (r16-validated): wfrag byte f = p*8192 + m*4096 + ni*1024 + l*16 + b
// o = ni*16 + (l&15), c = m*64 + (l>>4)*16 + b
__global__ __launch_bounds__(256) void k_prep(const float* __restrict__ cw,
                                              const float* __restrict__ b1,
                                              const float* __restrict__ pa,
                                              const float* __restrict__ b2,
                                              float* __restrict__ sf,
                                              float* __restrict__ theta,
                                              unsigned char* __restrict__ wf) {
    int b = blockIdx.x, t = threadIdx.x;    // 288 blocks
    int f = b * 256 + t;                    // < 73728
    int bb  = f & 15;
    int l   = (f >> 4) & 63;
    int ni  = (f >> 10) & 3;
    int m   = (f >> 12) & 1;
    int p   = f >> 13;
    int o = ni * 16 + (l & 15);
    int c = m * 64 + (l >> 4) * 16 + bb;
    float wv = cw[o * 1152 + c * 9 + p];
    wf[f] = wv > 0.f ? (unsigned char)0x01
                     : (wv < 0.f ? (unsigned char)0xFF : (unsigned char)0x00);
    if (b < 64) {                           // sf[b] = mean|w| over 1152
        __shared__ float red[4];
        const float* pp = cw + b * 1152;
        float s = 0.f;
        for (int i = t; i < 1152; i += 256) s += fabsf(pp[i]);
#pragma unroll
        for (int off = 32; off > 0; off >>= 1) s += __shfl_down(s, off);
        if ((t & 63) == 0) red[t >> 6] = s;
        __syncthreads();
        if (t == 0) sf[b] = (red[0] + red[1] + red[2] + red[3]) * (1.0f / 1152.0f);
    }
    if (b == 64 && t < NC) {                // theta: sign(prelu(v+b1)+b2) == sign(v - theta)
        float B1 = b1[t], A = pa[t], B2 = b2[t];   // prelu slope a>0 -> monotone
        theta[t] = (-B2 >= 0.f) ? (-B1 - B2) : (-B1 - B2 / A);
    }
}

__device__ __forceinline__ unsigned int pki8(float v, float th) {
    return v > th ? 0x01u : (v < th ? 0xFFu : 0u);
}

// ---------------- fused (r16 structure + pipelined staging + setprio):
// stage signs of 4 padded x-rows into LDS with 2-row load lookahead (XA/XB, branchless
// pad rows via clamped addr + uniform AND mask), shortcut in 64 regs,
// mfma_i32_16x16x64_i8, epilogue Tt tiles -> staging-mapped readout -> single write. ----
__global__ __launch_bounds__(256, 2) void k_fused(
    const float* __restrict__ x, const float* __restrict__ theta,
    const float* __restrict__ pw, const unsigned char* __restrict__ wf,
    const float* __restrict__ sf, float* __restrict__ out) {
    __shared__ __align__(16) unsigned char AT[69632];   // staging 66560 | Tt 4x17408
    int bxr = blockIdx.x;
    int bx = (bxr & 7) * 128 + (bxr >> 3);  // XCD swizzle (1024 % 8 == 0, bijective)
    int nb = bx >> 6;
    int h2b = bx & 63;
    int t = threadIdx.x;
    int wid = t >> 6;
    int l = t & 63;
    int lr = l & 15, lg = l >> 4;

    // ---- pad columns wp=0, 129 (always zero; 64 trivial stores) ----
    if (t < 64) {
        int rho = t >> 4, side = (t >> 3) & 1, u = t & 7;
        int wp = side ? (WP - 1) : 0;
        u32x4 z = {0u, 0u, 0u, 0u};
        *(u32x4*)(AT + (size_t)(rho * WP + wp) * NC + ((u ^ swz7(wp)) << 4)) = z;
    }

    // ---- staging: thread (w4 = t&31, cg = t>>5); 2-row software pipeline ----
    int w4 = t & 31, cg = t >> 5;
    const float* xbase = x + ((size_t)nb * NC + cg * 16) * (NH * NW) + 4 * w4;
    f32x4 th0 = *(const f32x4*)(theta + cg * 16);
    f32x4 th1 = *(const f32x4*)(theta + cg * 16 + 4);
    f32x4 th2 = *(const f32x4*)(theta + cg * 16 + 8);
    f32x4 th3 = *(const f32x4*)(theta + cg * 16 + 12);
    f32x4 p0 = *(const f32x4*)(pw + cg * 16);
    f32x4 p1 = *(const f32x4*)(pw + cg * 16 + 4);
    f32x4 p2 = *(const f32x4*)(pw + cg * 16 + 8);
    f32x4 p3 = *(const f32x4*)(pw + cg * 16 + 12);
    float pwv[16] = {p0.x, p0.y, p0.z, p0.w, p1.x, p1.y, p1.z, p1.w,
                     p2.x, p2.y, p2.z, p2.w, p3.x, p3.y, p3.z, p3.w};
    float sc0[8][4], sc1[8][4];             // shortcut regs, statically indexed
    f32x4 XA[16], XB[16];

#define ISSUE(XR, HH) \
    { const float* xp = xbase + (size_t)(HH) * NW; \
      _Pragma("unroll") for (int cc = 0; cc < 16; ++cc) \
          XR[cc] = *(const f32x4*)(xp + (size_t)cc * (NH * NW)); }
#define PACKROWM(RHO, XR, EM) \
    _Pragma("unroll") for (int ww = 0; ww < 4; ++ww) { \
        int wp = 4 * w4 + ww + 1; \
        u32x4 v; \
        v.x = (pki8(XR[0][ww], th0.x) | (pki8(XR[1][ww], th0.y) << 8) | \
               (pki8(XR[2][ww], th0.z) << 16) | (pki8(XR[3][ww], th0.w) << 24)) & (EM); \
        v.y = (pki8(XR[4][ww], th1.x) | (pki8(XR[5][ww], th1.y) << 8) | \
               (pki8(XR[6][ww], th1.z) << 16) | (pki8(XR[7][ww], th1.w) << 24)) & (EM); \
        v.z = (pki8(XR[8][ww], th2.x) | (pki8(XR[9][ww], th2.y) << 8) | \
               (pki8(XR[10][ww], th2.z) << 16) | (pki8(XR[11][ww], th2.w) << 24)) & (EM); \
        v.w = (pki8(XR[12][ww], th3.x) | (pki8(XR[13][ww], th3.y) << 8) | \
               (pki8(XR[14][ww], th3.z) << 16) | (pki8(XR[15][ww], th3.w) << 24)) & (EM); \
        *(u32x4*)(AT + (size_t)((RHO) * WP + wp) * NC + ((cg ^ swz7(wp)) << 4)) = v; \
    }
#define SCROW(SC, XR) \
    _Pragma("unroll") for (int i = 0; i < 8; ++i) { \
        float wa = pwv[2 * i], wb = pwv[2 * i + 1]; \
        _Pragma("unroll") for (int ww = 0; ww < 4; ++ww) \
            SC[i][ww] = wa * XR[2 * i][ww] + wb * XR[2 * i + 1][ww]; \
    }

    int hTop = (h2b > 0) ? (2 * h2b - 1) : 0;        // clamped (masked to zero below)
    int hBot = (h2b < 63) ? (2 * h2b + 2) : 127;
    unsigned emT = (h2b > 0) ? 0xFFFFFFFFu : 0u;     // block-uniform pad masks
    unsigned emB = (h2b < 63) ? 0xFFFFFFFFu : 0u;

    ISSUE(XA, hTop)                         // row 0 loads in flight
    ISSUE(XB, 2 * h2b)                      // row 1 loads in flight
    PACKROWM(0, XA, emT)
    ISSUE(XA, 2 * h2b + 1)                  // row 2 loads overlap row-0 pack
    PACKROWM(1, XB, 0xFFFFFFFFu)
    SCROW(sc0, XB)
    ISSUE(XB, hBot)                         // row 3 loads overlap row-1/2 pack
    PACKROWM(2, XA, 0xFFFFFFFFu)
    SCROW(sc1, XA)
    PACKROWM(3, XB, emB)

    float sfr[4];
#pragma unroll
    for (int ni = 0; ni < 4; ++ni) sfr[ni] = sf[ni * 16 + lr];

    int w0 = (wid & 1) * 64;                // output col base for this wave
    i32x4 acc[4][4];
    i32x4 zero = {0, 0, 0, 0};
#pragma unroll
    for (int mi = 0; mi < 4; ++mi)
#pragma unroll
        for (int ni = 0; ni < 4; ++ni) acc[mi][ni] = zero;
    __syncthreads();

    // ---- MFMA phase: i8 K=64; per-mi swizzle at actual col; setprio boost ----
    __builtin_amdgcn_s_setprio(1);
#pragma unroll
    for (int p = 0; p < 9; ++p) {
        int kh = p / 3, kw = p % 3;         // constants after unroll
        int rho = (wid >> 1) + kh;          // local padded row 0..3
        int wp = w0 + kw + lr;
        const unsigned char* ap = AT + (size_t)(rho * WP + wp) * NC;
        const unsigned char* brow = wf + p * 8192 + l * 16;
        i32x4 bfr[2][4];
#pragma unroll
        for (int m = 0; m < 2; ++m)         // B: 16B/lane coalesced, L2-hot
#pragma unroll
            for (int ni = 0; ni < 4; ++ni)
                bfr[m][ni] = *(const i32x4*)(brow + m * 4096 + ni * 1024);
#pragma unroll
        for (int mi = 0; mi < 4; ++mi) {    // 2 x ds_read_b128 = both K-halves
            int s7m = swz7(wp + mi * 16);   // swizzle of the column actually read
            i32x4 a0 = *(const i32x4*)(ap + mi * 2048 + ((lg ^ s7m) << 4));       // ch 16lg..+15
            i32x4 a1 = *(const i32x4*)(ap + mi * 2048 + (((lg + 4) ^ s7m) << 4)); // ch 64+16lg..
#pragma unroll
            for (int ni = 0; ni < 4; ++ni) {
                acc[mi][ni] = __builtin_amdgcn_mfma_i32_16x16x64_i8(
                    a0, bfr[0][ni], acc[mi][ni], 0, 0, 0);
                acc[mi][ni] = __builtin_amdgcn_mfma_i32_16x16x64_i8(
                    a1, bfr[1][ni], acc[mi][ni], 0, 0, 0);
            }
        }
    }
    __builtin_amdgcn_s_setprio(0);
    __syncthreads();                        // A-tile dead; AT becomes 4 x Tt[64][68]

    // ---- epilogue: full per-wave conv tile (i32 -> f32 * sf, f32x4 LDS writes) ----
    float (*Tt)[68] = (float (*)[68])(AT + wid * 17408);
#pragma unroll
    for (int mi = 0; mi < 4; ++mi)
#pragma unroll
        for (int ni = 0; ni < 4; ++ni) {
            f32x4 cv;
            cv.x = (float)acc[mi][ni].x * sfr[ni];
            cv.y = (float)acc[mi][ni].y * sfr[ni];
            cv.z = (float)acc[mi][ni].z * sfr[ni];
            cv.w = (float)acc[mi][ni].w * sfr[ni];
            *(f32x4*)&Tt[ni * 16 + lr][mi * 16 + lg * 4] = cv;
        }
    __syncthreads();

    // staging-mapped readout: thread (w4, cg) owns o in [8cg,8cg+8), cols 4w4..+3
    int wha = w4 >> 4, w4l = w4 & 15;
#define EPIROW(R2, SC) { \
    const float (*Ts)[68] = (const float (*)[68])(AT + ((R2) * 2 + wha) * 17408); \
    float* obr = out + (((size_t)nb * 256 + (R2) * 2) * 64 + h2b) * 64 + 2 * w4; \
    _Pragma("unroll") for (int i = 0; i < 8; ++i) { \
        int o = 8 * cg + i; \
        f32x4 cv = *(const f32x4*)&Ts[o][4 * w4l]; \
        float2 A = {cv.x + SC[i][0], cv.z + SC[i][2]}; \
        float2 B = {cv.y + SC[i][1], cv.w + SC[i][3]}; \
        *(float2*)(obr + (size_t)o * 16384)        = A; \
        *(float2*)(obr + (size_t)o * 16384 + 4096) = B; \
    } }
    EPIROW(0, sc0)
    EPIROW(1, sc1)
}

extern "C" void kernel_launch(void* const* d_in, const int* in_sizes, int n_in,
                              void* d_out, int out_size, void* d_ws, size_t ws_size,
                              hipStream_t stream) {
    const float* x  = (const float*)d_in[0];
    const float* b1 = (const float*)d_in[1];
    const float* pa = (const float*)d_in[2];
    const float* b2 = (const float*)d_in[3];
    const float* cw = (const float*)d_in[4];
    const float* pw = (const float*)d_in[5];
    float* out = (float*)d_out;
    // ws layout: [0,256) sf | [256,768) theta | [768, 768+73728) wfrag
    float* sf = (float*)d_ws;
    float* theta = (float*)((char*)d_ws + 256);
    unsigned char* wfr = (unsigned char*)d_ws + 768;

    k_prep<<<288, 256, 0, stream>>>(cw, b1, pa, b2, sf, theta, wfr);
    k_fused<<<1024, 256, 0, stream>>>(x, theta, pw, wfr, sf, out);
}

// Round 18
// 75.427 us; speedup vs baseline: 1.1994x; 1.0534x over previous
//
#include <hip/hip_runtime.h>
#include <stdint.h>

typedef __attribute__((ext_vector_type(4))) float f32x4;
typedef __attribute__((ext_vector_type(4))) unsigned int u32x4;
typedef __attribute__((ext_vector_type(4))) int i32x4;

#define NB 16
#define NC 128
#define NH 128
#define NW 128
#define WP 130

__device__ __forceinline__ int swz7(int wp) { return (wp ^ (wp >> 3)) & 7; }

// ---------------- prep: wfrag (B sign bytes, i8) + sf = mean|w| + theta ----------------
// i8 K=64 layout (r16-validated): wfrag byte f = p*8192 + m*4096 + ni*1024 + l*16 + b
// o = ni*16 + (l&15), c = m*64 + (l>>4)*16 + b
__global__ __launch_bounds__(256) void k_prep(const float* __restrict__ cw,
                                              const float* __restrict__ b1,
                                              const float* __restrict__ pa,
                                              const float* __restrict__ b2,
                                              float* __restrict__ sf,
                                              float* __restrict__ theta,
                                              unsigned char* __restrict__ wf) {
    int b = blockIdx.x, t = threadIdx.x;    // 288 blocks
    int f = b * 256 + t;                    // < 73728
    int bb  = f & 15;
    int l   = (f >> 4) & 63;
    int ni  = (f >> 10) & 3;
    int m   = (f >> 12) & 1;
    int p   = f >> 13;
    int o = ni * 16 + (l & 15);
    int c = m * 64 + (l >> 4) * 16 + bb;
    float wv = cw[o * 1152 + c * 9 + p];
    wf[f] = wv > 0.f ? (unsigned char)0x01
                     : (wv < 0.f ? (unsigned char)0xFF : (unsigned char)0x00);
    if (b < 64) {                           // sf[b] = mean|w| over 1152
        __shared__ float red[4];
        const float* pp = cw + b * 1152;
        float s = 0.f;
        for (int i = t; i < 1152; i += 256) s += fabsf(pp[i]);
#pragma unroll
        for (int off = 32; off > 0; off >>= 1) s += __shfl_down(s, off);
        if ((t & 63) == 0) red[t >> 6] = s;
        __syncthreads();
        if (t == 0) sf[b] = (red[0] + red[1] + red[2] + red[3]) * (1.0f / 1152.0f);
    }
    if (b == 64 && t < NC) {                // theta: sign(prelu(v+b1)+b2) == sign(v - theta)
        float B1 = b1[t], A = pa[t], B2 = b2[t];   // prelu slope a>0 -> monotone
        theta[t] = (-B2 >= 0.f) ? (-B1 - B2) : (-B1 - B2 / A);
    }
}

__device__ __forceinline__ unsigned int pki8(float v, float th) {
    return v > th ? 0x01u : (v < th ? 0xFFu : 0u);
}

// ---------------- fused (r17 + sched_barrier-pinned 3-deep staging pipeline):
// 48 x-loads (3 rows) forced in flight before any pack VALU via sched_barrier(0);
// shortcut in 64 regs, mfma_i32_16x16x64_i8, Tt-tile epilogue, single out write. ----
__global__ __launch_bounds__(256, 2) void k_fused(
    const float* __restrict__ x, const float* __restrict__ theta,
    const float* __restrict__ pw, const unsigned char* __restrict__ wf,
    const float* __restrict__ sf, float* __restrict__ out) {
    __shared__ __align__(16) unsigned char AT[69632];   // staging 66560 | Tt 4x17408
    int bxr = blockIdx.x;
    int bx = (bxr & 7) * 128 + (bxr >> 3);  // XCD swizzle (1024 % 8 == 0, bijective)
    int nb = bx >> 6;
    int h2b = bx & 63;
    int t = threadIdx.x;
    int wid = t >> 6;
    int l = t & 63;
    int lr = l & 15, lg = l >> 4;

    // ---- pad columns wp=0, 129 (always zero; 64 trivial stores) ----
    if (t < 64) {
        int rho = t >> 4, side = (t >> 3) & 1, u = t & 7;
        int wp = side ? (WP - 1) : 0;
        u32x4 z = {0u, 0u, 0u, 0u};
        *(u32x4*)(AT + (size_t)(rho * WP + wp) * NC + ((u ^ swz7(wp)) << 4)) = z;
    }

    // ---- staging: thread (w4 = t&31, cg = t>>5); 3-row forced-lookahead pipeline ----
    int w4 = t & 31, cg = t >> 5;
    const float* xbase = x + ((size_t)nb * NC + cg * 16) * (NH * NW) + 4 * w4;
    f32x4 th0 = *(const f32x4*)(theta + cg * 16);
    f32x4 th1 = *(const f32x4*)(theta + cg * 16 + 4);
    f32x4 th2 = *(const f32x4*)(theta + cg * 16 + 8);
    f32x4 th3 = *(const f32x4*)(theta + cg * 16 + 12);
    f32x4 p0 = *(const f32x4*)(pw + cg * 16);
    f32x4 p1 = *(const f32x4*)(pw + cg * 16 + 4);
    f32x4 p2 = *(const f32x4*)(pw + cg * 16 + 8);
    f32x4 p3 = *(const f32x4*)(pw + cg * 16 + 12);
    float pwv[16] = {p0.x, p0.y, p0.z, p0.w, p1.x, p1.y, p1.z, p1.w,
                     p2.x, p2.y, p2.z, p2.w, p3.x, p3.y, p3.z, p3.w};
    float sc0[8][4], sc1[8][4];             // shortcut regs, statically indexed
    f32x4 XA[16], XB[16], XC[16];

#define ISSUE(XR, HH) \
    { const float* xp = xbase + (size_t)(HH) * NW; \
      _Pragma("unroll") for (int cc = 0; cc < 16; ++cc) \
          XR[cc] = *(const f32x4*)(xp + (size_t)cc * (NH * NW)); }
#define PACKROWM(RHO, XR, EM) \
    _Pragma("unroll") for (int ww = 0; ww < 4; ++ww) { \
        int wp = 4 * w4 + ww + 1; \
        u32x4 v; \
        v.x = (pki8(XR[0][ww], th0.x) | (pki8(XR[1][ww], th0.y) << 8) | \
               (pki8(XR[2][ww], th0.z) << 16) | (pki8(XR[3][ww], th0.w) << 24)) & (EM); \
        v.y = (pki8(XR[4][ww], th1.x) | (pki8(XR[5][ww], th1.y) << 8) | \
               (pki8(XR[6][ww], th1.z) << 16) | (pki8(XR[7][ww], th1.w) << 24)) & (EM); \
        v.z = (pki8(XR[8][ww], th2.x) | (pki8(XR[9][ww], th2.y) << 8) | \
               (pki8(XR[10][ww], th2.z) << 16) | (pki8(XR[11][ww], th2.w) << 24)) & (EM); \
        v.w = (pki8(XR[12][ww], th3.x) | (pki8(XR[13][ww], th3.y) << 8) | \
               (pki8(XR[14][ww], th3.z) << 16) | (pki8(XR[15][ww], th3.w) << 24)) & (EM); \
        *(u32x4*)(AT + (size_t)((RHO) * WP + wp) * NC + ((cg ^ swz7(wp)) << 4)) = v; \
    }
#define SCROW(SC, XR) \
    _Pragma("unroll") for (int i = 0; i < 8; ++i) { \
        float wa = pwv[2 * i], wb = pwv[2 * i + 1]; \
        _Pragma("unroll") for (int ww = 0; ww < 4; ++ww) \
            SC[i][ww] = wa * XR[2 * i][ww] + wb * XR[2 * i + 1][ww]; \
    }

    int hTop = (h2b > 0) ? (2 * h2b - 1) : 0;        // clamped (masked to zero below)
    int hBot = (h2b < 63) ? (2 * h2b + 2) : 127;
    unsigned emT = (h2b > 0) ? 0xFFFFFFFFu : 0u;     // block-uniform pad masks
    unsigned emB = (h2b < 63) ? 0xFFFFFFFFu : 0u;

    ISSUE(XA, hTop)                         // 48 loads in flight before any pack
    ISSUE(XB, 2 * h2b)
    ISSUE(XC, 2 * h2b + 1)
    __builtin_amdgcn_sched_barrier(0);      // pin: issues may not sink below here
    PACKROWM(0, XA, emT)
    ISSUE(XA, hBot)                         // row 3 loads overlap row 1/2 pack
    __builtin_amdgcn_sched_barrier(0);
    PACKROWM(1, XB, 0xFFFFFFFFu)
    SCROW(sc0, XB)
    PACKROWM(2, XC, 0xFFFFFFFFu)
    SCROW(sc1, XC)
    PACKROWM(3, XA, emB)

    float sfr[4];
#pragma unroll
    for (int ni = 0; ni < 4; ++ni) sfr[ni] = sf[ni * 16 + lr];

    int w0 = (wid & 1) * 64;                // output col base for this wave
    i32x4 acc[4][4];
    i32x4 zero = {0, 0, 0, 0};
#pragma unroll
    for (int mi = 0; mi < 4; ++mi)
#pragma unroll
        for (int ni = 0; ni < 4; ++ni) acc[mi][ni] = zero;
    __syncthreads();

    // ---- MFMA phase: i8 K=64; per-mi swizzle at actual col; setprio boost ----
    __builtin_amdgcn_s_setprio(1);
#pragma unroll
    for (int p = 0; p < 9; ++p) {
        int kh = p / 3, kw = p % 3;         // constants after unroll
        int rho = (wid >> 1) + kh;          // local padded row 0..3
        int wp = w0 + kw + lr;
        const unsigned char* ap = AT + (size_t)(rho * WP + wp) * NC;
        const unsigned char* brow = wf + p * 8192 + l * 16;
        i32x4 bfr[2][4];
#pragma unroll
        for (int m = 0; m < 2; ++m)         // B: 16B/lane coalesced, L2-hot
#pragma unroll
            for (int ni = 0; ni < 4; ++ni)
                bfr[m][ni] = *(const i32x4*)(brow + m * 4096 + ni * 1024);
#pragma unroll
        for (int mi = 0; mi < 4; ++mi) {    // 2 x ds_read_b128 = both K-halves
            int s7m = swz7(wp + mi * 16);   // swizzle of the column actually read
            i32x4 a0 = *(const i32x4*)(ap + mi * 2048 + ((lg ^ s7m) << 4));       // ch 16lg..+15
            i32x4 a1 = *(const i32x4*)(ap + mi * 2048 + (((lg + 4) ^ s7m) << 4)); // ch 64+16lg..
#pragma unroll
            for (int ni = 0; ni < 4; ++ni) {
                acc[mi][ni] = __builtin_amdgcn_mfma_i32_16x16x64_i8(
                    a0, bfr[0][ni], acc[mi][ni], 0, 0, 0);
                acc[mi][ni] = __builtin_amdgcn_mfma_i32_16x16x64_i8(
                    a1, bfr[1][ni], acc[mi][ni], 0, 0, 0);
            }
        }
    }
    __builtin_amdgcn_s_setprio(0);
    __syncthreads();                        // A-tile dead; AT becomes 4 x Tt[64][68]

    // ---- epilogue: full per-wave conv tile (i32 -> f32 * sf, f32x4 LDS writes) ----
    float (*Tt)[68] = (float (*)[68])(AT + wid * 17408);
#pragma unroll
    for (int mi = 0; mi < 4; ++mi)
#pragma unroll
        for (int ni = 0; ni < 4; ++ni) {
            f32x4 cv;
            cv.x = (float)acc[mi][ni].x * sfr[ni];
            cv.y = (float)acc[mi][ni].y * sfr[ni];
            cv.z = (float)acc[mi][ni].z * sfr[ni];
            cv.w = (float)acc[mi][ni].w * sfr[ni];
            *(f32x4*)&Tt[ni * 16 + lr][mi * 16 + lg * 4] = cv;
        }
    __syncthreads();

    // staging-mapped readout: thread (w4, cg) owns o in [8cg,8cg+8), cols 4w4..+3
    int wha = w4 >> 4, w4l = w4 & 15;
#define EPIROW(R2, SC) { \
    const float (*Ts)[68] = (const float (*)[68])(AT + ((R2) * 2 + wha) * 17408); \
    float* obr = out + (((size_t)nb * 256 + (R2) * 2) * 64 + h2b) * 64 + 2 * w4; \
    _Pragma("unroll") for (int i = 0; i < 8; ++i) { \
        int o = 8 * cg + i; \
        f32x4 cv = *(const f32x4*)&Ts[o][4 * w4l]; \
        float2 A = {cv.x + SC[i][0], cv.z + SC[i][2]}; \
        float2 B = {cv.y + SC[i][1], cv.w + SC[i][3]}; \
        *(float2*)(obr + (size_t)o * 16384)        = A; \
        *(float2*)(obr + (size_t)o * 16384 + 4096) = B; \
    } }
    EPIROW(0, sc0)
    EPIROW(1, sc1)
}

extern "C" void kernel_launch(void* const* d_in, const int* in_sizes, int n_in,
                              void* d_out, int out_size, void* d_ws, size_t ws_size,
                              hipStream_t stream) {
    const float* x  = (const float*)d_in[0];
    const float* b1 = (const float*)d_in[1];
    const float* pa = (const float*)d_in[2];
    const float* b2 = (const float*)d_in[3];
    const float* cw = (const float*)d_in[4];
    const float* pw = (const float*)d_in[5];
    float* out = (float*)d_out;
    // ws layout: [0,256) sf | [256,768) theta | [768, 768+73728) wfrag
    float* sf = (float*)d_ws;
    float* theta = (float*)((char*)d_ws + 256);
    unsigned char* wfr = (unsigned char*)d_ws + 768;

    k_prep<<<288, 256, 0, stream>>>(cw, b1, pa, b2, sf, theta, wfr);
    k_fused<<<1024, 256, 0, stream>>>(x, theta, pw, wfr, sf, out);
}